// Round 2
// baseline (251.261 us; speedup 1.0000x reference)
//
#include <hip/hip_runtime.h>

// Problem constants (reference: B=32, N=1024, D=384, max_len=4096)
#define BB 32
#define NN 1024
#define DD 384
#define ML 4096
#define D4 (DD / 4)              // 96 float4 per row
#define TOTF4 (BB * ML * D4)     // 12,582,912 float4 in out
#define CT 256                   // copy block threads
#define NBLK (TOTF4 / CT)        // 49152 copy blocks (divisible by 8)

// Kernel 1: per-batch scan of durations + scatter-inverse of searchsorted.
// 32 blocks x 256 threads; shuffle-based scan (3 barriers total).
// Produces idxb[b][t] (x-row index, -1 if t >= total) and mask[b][t].
__global__ __launch_bounds__(CT) void lr_scan_kernel(
    const int4* __restrict__ dur4, int* __restrict__ idxb,
    float* __restrict__ mask) {
    __shared__ __align__(16) int idx_lds[ML];   // 16 KB
    __shared__ int wsum[CT / 64];
    const int b    = blockIdx.x;
    const int tid  = threadIdx.x;
    const int lane = tid & 63;
    const int wid  = tid >> 6;

    // Load 4 durations; init idx_lds to -1 (independent work, same barrier).
    int4 d = dur4[b * (NN / 4) + tid];
    int4* lds4 = reinterpret_cast<int4*>(idx_lds);
    #pragma unroll
    for (int k = 0; k < ML / 4 / CT; ++k)
        lds4[tid + k * CT] = make_int4(-1, -1, -1, -1);

    // Wave-inclusive scan of per-thread 4-sums (no barriers).
    int s = d.x + d.y + d.z + d.w;
    #pragma unroll
    for (int off = 1; off < 64; off <<= 1) {
        int n = __shfl_up(s, off);
        if (lane >= off) s += n;
    }
    if (lane == 63) wsum[wid] = s;
    __syncthreads();                 // covers wsum + idx_lds init
    int woff = 0;
    #pragma unroll
    for (int w = 0; w < CT / 64 - 1; ++w)
        if (w < wid) woff += wsum[w];

    // Element-level inclusive cums for this thread's 4 source rows.
    int c3 = woff + s;               // cum[4*tid+3]
    int c2 = c3 - d.w;
    int c1 = c2 - d.z;
    int c0 = c1 - d.y;
    int p  = c0 - d.x;               // cum[4*tid-1] (exclusive start)

    // Scatter-inverse: source row i owns t in [cum[i-1], cum[i]), clamp ML.
    const int i0 = tid * 4;
    int lo, hi;
    lo = p;  hi = (c0 < ML) ? c0 : ML; for (int t = lo; t < hi; ++t) idx_lds[t] = i0;
    lo = c0; hi = (c1 < ML) ? c1 : ML; for (int t = lo; t < hi; ++t) idx_lds[t] = i0 + 1;
    lo = c1; hi = (c2 < ML) ? c2 : ML; for (int t = lo; t < hi; ++t) idx_lds[t] = i0 + 2;
    lo = c2; hi = (c3 < ML) ? c3 : ML; for (int t = lo; t < hi; ++t) idx_lds[t] = i0 + 3;
    __syncthreads();

    // Write idx + mask, vectorized (4 int4 + 4 float4 per thread).
    int4* idxb4 = reinterpret_cast<int4*>(idxb + b * ML);
    float4* mask4 = reinterpret_cast<float4*>(mask + b * ML);
    #pragma unroll
    for (int k = 0; k < ML / 4 / CT; ++k) {
        const int4 v = lds4[tid + k * CT];
        idxb4[tid + k * CT] = v;
        float4 m;
        m.x = (v.x < 0) ? 1.0f : 0.0f;
        m.y = (v.y < 0) ? 1.0f : 0.0f;
        m.z = (v.z < 0) ? 1.0f : 0.0f;
        m.w = (v.w < 0) ? 1.0f : 0.0f;
        mask4[tid + k * CT] = m;
    }
}

// Kernel 2: fill-shaped flat gather-copy. One float4 per thread, no LDS,
// no barriers, minimal VGPRs — mimics the rocclr fill that sustains
// 6.5 TB/s at ~10% occupancy. Stores are exactly sequential in gid.
__global__ __launch_bounds__(CT) void lr_flat_copy_kernel(
    const float4* __restrict__ x, const int* __restrict__ idxb,
    float4* __restrict__ out) {
    // XCD-aware swizzle: contiguous gid range per XCD -> each XCD's x slice
    // stays small and L2-resident (perf heuristic only).
    const int g   = ((blockIdx.x & 7) * (NBLK / 8)) + (blockIdx.x >> 3);
    const int gid = g * CT + threadIdx.x;
    const int row = gid / D4;            // const-div -> magic mul
    const int d4  = gid - row * D4;
    const int idx = idxb[row];           // L1-broadcast (96 threads share)
    float4 v = {0.0f, 0.0f, 0.0f, 0.0f};
    if (idx >= 0) {
        const int b = row >> 12;         // row / ML
        v = x[((b << 10) + idx) * D4 + d4];
    }
    out[gid] = v;
}

extern "C" void kernel_launch(void* const* d_in, const int* in_sizes, int n_in,
                              void* d_out, int out_size, void* d_ws, size_t ws_size,
                              hipStream_t stream) {
    const float* x = (const float*)d_in[0];
    const int* dur = (const int*)d_in[1];
    // d_in[2] is max_len scalar; fixed at 4096 for this problem instance.

    int* idxb   = (int*)d_ws;                      // B*ML ints = 512 KB scratch
    float* out  = (float*)d_out;                   // (B, ML, D) fp32
    float* mask = out + (size_t)BB * ML * DD;      // (B, ML) as fp32 0/1

    lr_scan_kernel<<<BB, CT, 0, stream>>>((const int4*)dur, idxb, mask);
    lr_flat_copy_kernel<<<NBLK, CT, 0, stream>>>(
        (const float4*)x, idxb, (float4*)out);
}

// Round 3
// 249.355 us; speedup vs baseline: 1.0076x; 1.0076x over previous
//
#include <hip/hip_runtime.h>

// Problem constants (reference: B=32, N=1024, D=384, max_len=4096)
#define BB 32
#define NN 1024
#define DD 384
#define ML 4096
#define D4 (DD / 4)              // 96 float4 per row
#define TOTF4 (BB * ML * D4)     // 12,582,912 float4 in out
#define CT 256                   // threads per block
#define CB 2048                  // copy blocks (guideline-11 sizing; %8==0)
#define F4B (TOTF4 / CB)         // 6144 f4 per block = 64 contiguous rows
#define KIT (F4B / CT)           // 24 f4 per thread
#define GRP 8                    // MLP depth per group
#define NGRP (KIT / GRP)         // 3 groups

typedef float f32x4 __attribute__((ext_vector_type(4)));

// Kernel 1: per-batch scan of durations + scatter-inverse of searchsorted.
// 32 blocks x 256 threads; shuffle-based scan. Produces idxb[b][t]
// (x-row index, -1 if t >= total) and mask[b][t]. ~4 us.
__global__ __launch_bounds__(CT) void lr_scan_kernel(
    const int4* __restrict__ dur4, int* __restrict__ idxb,
    float* __restrict__ mask) {
    __shared__ __align__(16) int idx_lds[ML];   // 16 KB
    __shared__ int wsum[CT / 64];
    const int b    = blockIdx.x;
    const int tid  = threadIdx.x;
    const int lane = tid & 63;
    const int wid  = tid >> 6;

    int4 d = dur4[b * (NN / 4) + tid];
    int4* lds4 = reinterpret_cast<int4*>(idx_lds);
    #pragma unroll
    for (int k = 0; k < ML / 4 / CT; ++k)
        lds4[tid + k * CT] = make_int4(-1, -1, -1, -1);

    int s = d.x + d.y + d.z + d.w;
    #pragma unroll
    for (int off = 1; off < 64; off <<= 1) {
        int n = __shfl_up(s, off);
        if (lane >= off) s += n;
    }
    if (lane == 63) wsum[wid] = s;
    __syncthreads();                 // covers wsum + idx_lds init
    int woff = 0;
    #pragma unroll
    for (int w = 0; w < CT / 64 - 1; ++w)
        if (w < wid) woff += wsum[w];

    int c3 = woff + s;               // cum[4*tid+3]
    int c2 = c3 - d.w;
    int c1 = c2 - d.z;
    int c0 = c1 - d.y;
    int p  = c0 - d.x;               // exclusive start

    const int i0 = tid * 4;
    int lo, hi;
    lo = p;  hi = (c0 < ML) ? c0 : ML; for (int t = lo; t < hi; ++t) idx_lds[t] = i0;
    lo = c0; hi = (c1 < ML) ? c1 : ML; for (int t = lo; t < hi; ++t) idx_lds[t] = i0 + 1;
    lo = c1; hi = (c2 < ML) ? c2 : ML; for (int t = lo; t < hi; ++t) idx_lds[t] = i0 + 2;
    lo = c2; hi = (c3 < ML) ? c3 : ML; for (int t = lo; t < hi; ++t) idx_lds[t] = i0 + 3;
    __syncthreads();

    int4* idxb4 = reinterpret_cast<int4*>(idxb + b * ML);
    float4* mask4 = reinterpret_cast<float4*>(mask + b * ML);
    #pragma unroll
    for (int k = 0; k < ML / 4 / CT; ++k) {
        const int4 v = lds4[tid + k * CT];
        idxb4[tid + k * CT] = v;
        float4 m;
        m.x = (v.x < 0) ? 1.0f : 0.0f;
        m.y = (v.y < 0) ? 1.0f : 0.0f;
        m.z = (v.z < 0) ? 1.0f : 0.0f;
        m.w = (v.w < 0) ? 1.0f : 0.0f;
        mask4[tid + k * CT] = m;
    }
}

// Kernel 2: deep-MLP gather-copy. 2048 blocks; each block owns a contiguous
// 1.5 MB / 64-row slice of out (XCD swizzle keeps per-XCD x slice small).
// Per thread: 3 groups of {prefetch 8 independent idxb, 8 independent x
// loads, 8 nontemporal stores} -> 8-deep MLP breaks the idxb->x dependent-
// chain latency that capped prior variants at ~2.1 TB/s.
__global__ __launch_bounds__(CT) void lr_copy_kernel(
    const float4* __restrict__ x, const int* __restrict__ idxb,
    float4* __restrict__ out) {
    // XCD-aware swizzle: contiguous block range per XCD (perf heuristic).
    const int g    = ((blockIdx.x & 7) * (CB / 8)) + (blockIdx.x >> 3);
    const int base = g * F4B + threadIdx.x;   // this thread's k=0 f4 index

    #pragma unroll
    for (int grp = 0; grp < NGRP; ++grp) {
        int    idxv[GRP];
        float4 v[GRP];
        // Phase 1: 8 independent idxb loads (row = address arithmetic only).
        #pragma unroll
        for (int j = 0; j < GRP; ++j) {
            const int gid = base + (grp * GRP + j) * CT;
            const int row = gid / D4;          // const-div -> magic mul
            idxv[j] = idxb[row];               // L1-broadcast across lanes
        }
        // Phase 2: 8 independent x loads (predicated).
        #pragma unroll
        for (int j = 0; j < GRP; ++j) {
            const int gid = base + (grp * GRP + j) * CT;
            const int row = gid / D4;
            const int d4  = gid - row * D4;
            const int b   = row >> 12;         // row / ML
            v[j] = make_float4(0.0f, 0.0f, 0.0f, 0.0f);
            if (idxv[j] >= 0)
                v[j] = x[((b << 10) + idxv[j]) * D4 + d4];
        }
        // Phase 3: 8 coalesced nontemporal stores (out never re-read).
        #pragma unroll
        for (int j = 0; j < GRP; ++j) {
            const int gid = base + (grp * GRP + j) * CT;
            f32x4* dst = reinterpret_cast<f32x4*>(&out[gid]);
            __builtin_nontemporal_store(*reinterpret_cast<f32x4*>(&v[j]), dst);
        }
    }
}

extern "C" void kernel_launch(void* const* d_in, const int* in_sizes, int n_in,
                              void* d_out, int out_size, void* d_ws, size_t ws_size,
                              hipStream_t stream) {
    const float* x = (const float*)d_in[0];
    const int* dur = (const int*)d_in[1];
    // d_in[2] is max_len scalar; fixed at 4096 for this problem instance.

    int* idxb   = (int*)d_ws;                      // B*ML ints = 512 KB scratch
    float* out  = (float*)d_out;                   // (B, ML, D) fp32
    float* mask = out + (size_t)BB * ML * DD;      // (B, ML) as fp32 0/1

    lr_scan_kernel<<<BB, CT, 0, stream>>>((const int4*)dur, idxb, mask);
    lr_copy_kernel<<<CB, CT, 0, stream>>>(
        (const float4*)x, idxb, (float4*)out);
}